// Round 13
// baseline (319.033 us; speedup 1.0000x reference)
//
#include <hip/hip_runtime.h>
#include <math.h>

#define NEG_SLOPE 0.2f
#define EPS_GAT 1e-16f
#define LOG2E 1.4426950408889634f
typedef unsigned int u32;
typedef unsigned short u16;
typedef __attribute__((ext_vector_type(8))) short short8;   // 8 bf16 (4 VGPRs)
typedef __attribute__((ext_vector_type(4))) float f32x4;

// ---- bf16 helpers ----
__device__ inline u16 f2bf(float x) {
    union { float f; u32 u; } v; v.f = x;
    u32 r = v.u + 0x7FFFu + ((v.u >> 16) & 1u);   // RNE
    return (u16)(r >> 16);
}
__device__ inline float bf_lo(u32 u) {
    union { u32 i; float f; } v; v.i = u << 16; return v.f;
}
__device__ inline float bf_hi(u32 u) {
    union { u32 i; float f; } v; v.i = u & 0xFFFF0000u; return v.f;
}
__device__ inline float bf1(u16 s) {
    union { u32 i; float f; } v; v.i = ((u32)s) << 16; return v.f;
}
__device__ inline float fast_exp2(float x) {
#if __has_builtin(__builtin_amdgcn_exp2f)
    return __builtin_amdgcn_exp2f(x);
#else
    return exp2f(x);
#endif
}
// logits pre-scaled by LOG2E; lrelu commutes with positive scaling.
__device__ inline float lrelu_exp2(float t) {
    return fast_exp2(fmaxf(t, NEG_SLOPE * t));
}

// ---------------- prep + degree (no LDS -> full occupancy for the atomics) ----------------
// b < 64: W1 hi/lo split.  b == 64: W2 fold.  b > 64: degree histogram + rank.

__global__ void prep_degree_kernel(const float* __restrict__ W1,
                                   u16* __restrict__ w1t_hi, u16* __restrict__ w1t_lo,
                                   const float* __restrict__ W2, const float* __restrict__ a2s,
                                   const float* __restrict__ a2d, float* __restrict__ w_as,
                                   float* __restrict__ w_ad,
                                   const int* __restrict__ dst, int E,
                                   int* __restrict__ counts, int* __restrict__ rank) {
    int b = blockIdx.x;
    int tid = threadIdx.x;
    if (b < 64) {
        int i = b * 256 + tid;   // 16384
        int k = i >> 7, n = i & 127;
        float w = W1[i];
        u16 hi = f2bf(w);
        u16 lo = f2bf(w - bf1(hi));
        w1t_hi[n * 128 + k] = hi;
        w1t_lo[n * 128 + k] = lo;
    } else if (b == 64) {
        if (tid < 128) {
            int h = tid >> 5, k = tid & 31;
            float s1 = 0.f, s2 = 0.f;
#pragma unroll
            for (int f = 0; f < 16; ++f) {
                float w = W2[k * 64 + h * 16 + f];
                s1 += w * a2s[h * 16 + f];
                s2 += w * a2d[h * 16 + f];
            }
            w_as[h * 32 + k] = s1;
            w_ad[h * 32 + k] = s2;
        }
    } else {
        int nd = gridDim.x - 65;
        for (int e = (b - 65) * 256 + tid; e < E; e += nd * 256)
            rank[e] = atomicAdd(&counts[dst[e]], 1);
    }
}

// ---------------- GEMM1 via MFMA (hi/lo split, fp32-grade) + fused attn1 ----------------

__global__ __launch_bounds__(256) void gemm1_mfma_kernel(const float* __restrict__ X,
                                                         const u16* __restrict__ w1t_hi,
                                                         const u16* __restrict__ w1t_lo,
                                                         const float* __restrict__ a_src,
                                                         const float* __restrict__ a_dst,
                                                         u16* __restrict__ Hb,
                                                         float* __restrict__ as_,
                                                         float* __restrict__ ad_, int N) {
    __shared__ __align__(16) u16 xsh_hi[64 * 40];
    __shared__ __align__(16) u16 xsh_lo[64 * 40];
    __shared__ __align__(16) u16 wbuf[10240];     // W staging hi|lo; h-tile after K-loop
    __shared__ float ash[128], adsh[128];
    int tid = threadIdx.x;
    int wave = tid >> 6, lane = tid & 63, quad = lane >> 4;
    int m0 = blockIdx.x * 64;

    if (tid < 128) { ash[tid] = a_src[tid]; adsh[tid] = a_dst[tid]; }
    u16* wsh_hi = wbuf;
    u16* wsh_lo = wbuf + 5120;
    int xrow = tid >> 2, xkq = (tid & 3) * 8;

    f32x4 acc[4][2];
#pragma unroll
    for (int rt = 0; rt < 4; ++rt)
#pragma unroll
        for (int ct = 0; ct < 2; ++ct) acc[rt][ct] = (f32x4)(0.f);

    for (int k0 = 0; k0 < 128; k0 += 32) {
        {
            int gr = m0 + xrow;
            float f[8];
            *(float4*)&f[0] = (gr < N) ? *(const float4*)(X + (size_t)gr * 128 + k0 + xkq)
                                       : make_float4(0.f, 0.f, 0.f, 0.f);
            *(float4*)&f[4] = (gr < N) ? *(const float4*)(X + (size_t)gr * 128 + k0 + xkq + 4)
                                       : make_float4(0.f, 0.f, 0.f, 0.f);
            u16 hi[8], lo[8];
#pragma unroll
            for (int i = 0; i < 8; ++i) {
                hi[i] = f2bf(f[i]);
                lo[i] = f2bf(f[i] - bf1(hi[i]));
            }
            *(uint4*)&xsh_hi[xrow * 40 + xkq] = *(uint4*)hi;
            *(uint4*)&xsh_lo[xrow * 40 + xkq] = *(uint4*)lo;
        }
        {
#pragma unroll
            for (int i = 0; i < 2; ++i) {
                int id = tid * 2 + i;
                int n = id >> 2, part = id & 3;
                *(uint4*)&wsh_hi[n * 40 + part * 8] =
                    ((const uint4*)(w1t_hi + n * 128 + k0))[part];
                *(uint4*)&wsh_lo[n * 40 + part * 8] =
                    ((const uint4*)(w1t_lo + n * 128 + k0))[part];
            }
        }
        __syncthreads();

        short8 bhi[2], blo[2];
#pragma unroll
        for (int ct = 0; ct < 2; ++ct) {
            int n = wave * 32 + ct * 16 + (lane & 15);
            bhi[ct] = *(const short8*)&wsh_hi[n * 40 + quad * 8];
            blo[ct] = *(const short8*)&wsh_lo[n * 40 + quad * 8];
        }
#pragma unroll
        for (int rt = 0; rt < 4; ++rt) {
            int m = rt * 16 + (lane & 15);
            short8 ahi = *(const short8*)&xsh_hi[m * 40 + quad * 8];
            short8 alo = *(const short8*)&xsh_lo[m * 40 + quad * 8];
#pragma unroll
            for (int ct = 0; ct < 2; ++ct) {
                acc[rt][ct] = __builtin_amdgcn_mfma_f32_16x16x32_bf16(ahi, bhi[ct], acc[rt][ct], 0, 0, 0);
                acc[rt][ct] = __builtin_amdgcn_mfma_f32_16x16x32_bf16(alo, bhi[ct], acc[rt][ct], 0, 0, 0);
                acc[rt][ct] = __builtin_amdgcn_mfma_f32_16x16x32_bf16(ahi, blo[ct], acc[rt][ct], 0, 0, 0);
            }
        }
        __syncthreads();
    }

    // h-tile -> global + LDS (stride 130 u16; 16640 B <= 20480 B of wbuf)
    const int HS = 130;
#pragma unroll
    for (int rt = 0; rt < 4; ++rt)
#pragma unroll
        for (int ct = 0; ct < 2; ++ct) {
            int col = wave * 32 + ct * 16 + (lane & 15);
#pragma unroll
            for (int r = 0; r < 4; ++r) {
                int row = rt * 16 + quad * 4 + r;
                u16 hv = f2bf(acc[rt][ct][r]);
                int gr = m0 + row;
                if (gr < N) Hb[(size_t)gr * 128 + col] = hv;
                wbuf[row * HS + col] = hv;
            }
        }
    __syncthreads();

    // fused attn1: one thread per (row, head)
    {
        int row = tid >> 2, h = tid & 3;
        int gr = m0 + row;
        if (gr < N) {
            const u32* hr = (const u32*)&wbuf[row * HS + h * 32];
            float s1 = 0.f, s2 = 0.f;
#pragma unroll
            for (int q = 0; q < 16; ++q) {
                u32 u = hr[q];
                float flo = bf_lo(u), fhi = bf_hi(u);
                s1 += flo * ash[h * 32 + 2 * q] + fhi * ash[h * 32 + 2 * q + 1];
                s2 += flo * adsh[h * 32 + 2 * q] + fhi * adsh[h * 32 + 2 * q + 1];
            }
            as_[(size_t)gr * 4 + h] = s1 * LOG2E;
            ad_[(size_t)gr * 4 + h] = s2 * LOG2E;
        }
    }
}

// ---------------- scan: per-1024-chunk inclusive + last-block partials scan ----------------

__global__ __launch_bounds__(1024) void scan_kernel(const int* __restrict__ counts, int N,
                                                    int* __restrict__ scanned,
                                                    int* __restrict__ bsums,
                                                    int* __restrict__ done, int nchunks) {
    __shared__ int tmp[1024];
    __shared__ int flag;
    int tid = threadIdx.x;
    int i = (blockIdx.x << 10) + tid;
    int v = (i < N) ? counts[i] : 0;
    tmp[tid] = v;
    __syncthreads();
    for (int d = 1; d < 1024; d <<= 1) {
        int t = (tid >= d) ? tmp[tid - d] : 0;
        __syncthreads();
        tmp[tid] += t;
        __syncthreads();
    }
    if (i < N) scanned[i] = tmp[tid];
    if (tid == 1023) bsums[blockIdx.x] = tmp[1023];
    __syncthreads();
    if (tid == 0) {
        __threadfence();                        // publish bsums
        int prev = atomicAdd(done, 1);
        flag = (prev == (int)gridDim.x - 1);
    }
    __syncthreads();
    if (flag) {                                 // last block scans partials
        __threadfence();                        // acquire other blocks' bsums
        int vv = (tid < nchunks) ? bsums[tid] : 0;
        tmp[tid] = vv;
        __syncthreads();
        for (int d = 1; d < 1024; d <<= 1) {
            int t = (tid >= d) ? tmp[tid - d] : 0;
            __syncthreads();
            tmp[tid] += t;
            __syncthreads();
        }
        if (tid < nchunks) bsums[tid] = tmp[tid] - vv;   // exclusive
    }
}

// ---------------- fill CSR + finalize row_off (one kernel, no atomics) ----------------

__global__ void fill_finalize_kernel(const int* __restrict__ src, const int* __restrict__ dst,
                                     int E, int N, const int* __restrict__ counts,
                                     const int* __restrict__ scanned, const int* __restrict__ bsums,
                                     const int* __restrict__ rank, int* __restrict__ row_off,
                                     int* __restrict__ csr_src) {
    int t = blockIdx.x * blockDim.x + threadIdx.x;
    if (t <= N)
        row_off[t] = (t == 0) ? 0 : scanned[t - 1] + bsums[(t - 1) >> 10];
    if (t < E) {
        int d = dst[t];
        int startd = scanned[d] + bsums[d >> 10] - counts[d];
        csr_src[startd + rank[t]] = src[t];
    }
}

// ---------------- layer-1 aggregate + fused attn2 epilogue ----------------

__global__ __launch_bounds__(256, 8) void node_agg128_kernel(const u32* __restrict__ Hb,
                                                             const float* __restrict__ as_,
                                                             const float* __restrict__ ad_,
                                                             const int* __restrict__ row_off,
                                                             const int* __restrict__ csr_src,
                                                             const float* __restrict__ bias,
                                                             const float* __restrict__ w_as,
                                                             const float* __restrict__ w_ad,
                                                             u32* __restrict__ O1,
                                                             float* __restrict__ as2,
                                                             float* __restrict__ ad2, int N) {
    int lane = threadIdx.x & 63;
    int node = __builtin_amdgcn_readfirstlane(blockIdx.x * 4 + (threadIdx.x >> 6));
    if (node >= N) return;
    int start = __builtin_amdgcn_readfirstlane(row_off[node]);
    int end   = __builtin_amdgcn_readfirstlane(row_off[node + 1]);
    int deg = end - start;
    int h = lane >> 4;
    float adh = ad_[node * 4 + h];

    int clamp = (deg > 0) ? deg - 1 : 0;
    int vidx = csr_src[start + min(lane, clamp)];
    int m = min(deg, 64);

    float2 acc = make_float2(0.f, 0.f);
    float den = 0.f;
    int j = 0;
    for (; j + 4 <= m; j += 4) {
        int s0 = __builtin_amdgcn_readlane(vidx, j);
        int s1 = __builtin_amdgcn_readlane(vidx, j + 1);
        int s2 = __builtin_amdgcn_readlane(vidx, j + 2);
        int s3 = __builtin_amdgcn_readlane(vidx, j + 3);
        float a0 = as_[s0 * 4 + h], a1 = as_[s1 * 4 + h];
        float a2 = as_[s2 * 4 + h], a3 = as_[s3 * 4 + h];
        u32 u0 = Hb[s0 * 64 + lane];
        u32 u1 = Hb[s1 * 64 + lane];
        u32 u2 = Hb[s2 * 64 + lane];
        u32 u3 = Hb[s3 * 64 + lane];
        float e0 = lrelu_exp2(a0 + adh), e1 = lrelu_exp2(a1 + adh);
        float e2 = lrelu_exp2(a2 + adh), e3 = lrelu_exp2(a3 + adh);
        acc.x = fmaf(e0, bf_lo(u0), acc.x); acc.y = fmaf(e0, bf_hi(u0), acc.y); den += e0;
        acc.x = fmaf(e1, bf_lo(u1), acc.x); acc.y = fmaf(e1, bf_hi(u1), acc.y); den += e1;
        acc.x = fmaf(e2, bf_lo(u2), acc.x); acc.y = fmaf(e2, bf_hi(u2), acc.y); den += e2;
        acc.x = fmaf(e3, bf_lo(u3), acc.x); acc.y = fmaf(e3, bf_hi(u3), acc.y); den += e3;
    }
    for (; j < m; ++j) {
        int s = __builtin_amdgcn_readlane(vidx, j);
        float e = lrelu_exp2(as_[s * 4 + h] + adh);
        u32 u = Hb[s * 64 + lane];
        acc.x = fmaf(e, bf_lo(u), acc.x); acc.y = fmaf(e, bf_hi(u), acc.y); den += e;
    }
    for (int jj = start + 64; jj < end; ++jj) {   // deg>64 fallback
        int s = __builtin_amdgcn_readfirstlane(csr_src[jj]);
        float e = lrelu_exp2(as_[s * 4 + h] + adh);
        u32 u = Hb[s * 64 + lane];
        acc.x = fmaf(e, bf_lo(u), acc.x); acc.y = fmaf(e, bf_hi(u), acc.y); den += e;
    }
    float inv = 1.f / (den + EPS_GAT);
    float px = acc.x * inv, py = acc.y * inv;
    px += __shfl_xor(px, 16); py += __shfl_xor(py, 16);
    px += __shfl_xor(px, 32); py += __shfl_xor(py, 32);

    int f2 = (lane & 15) * 2;
    float2 bv = *(const float2*)&bias[f2];
    float ox = fmaxf(px * 0.25f + bv.x, 0.f);
    float oy = fmaxf(py * 0.25f + bv.y, 0.f);
    if (lane < 16)
        O1[node * 16 + lane] = (u32)f2bf(ox) | ((u32)f2bf(oy) << 16);

    // fused attn2 (16-lane xor reduction)
    int h2 = lane >> 4;
    float2 wa = *(const float2*)&w_as[h2 * 32 + f2];
    float2 wd = *(const float2*)&w_ad[h2 * 32 + f2];
    float ta = ox * wa.x + oy * wa.y;
    float td = ox * wd.x + oy * wd.y;
    ta += __shfl_xor(ta, 1); td += __shfl_xor(td, 1);
    ta += __shfl_xor(ta, 2); td += __shfl_xor(td, 2);
    ta += __shfl_xor(ta, 4); td += __shfl_xor(td, 4);
    ta += __shfl_xor(ta, 8); td += __shfl_xor(td, 8);
    if ((lane & 15) == 0) {
        as2[node * 4 + h2] = ta * LOG2E;
        ad2[node * 4 + h2] = td * LOG2E;
    }
}

// ---------------- layer-2 aggregate + fused W2 epilogue (readlane layout) ----------------

__global__ __launch_bounds__(256, 8) void node_agg32_fused_kernel(const u32* __restrict__ O1,
                                                                  const float* __restrict__ as_,
                                                                  const float* __restrict__ ad_,
                                                                  const int* __restrict__ row_off,
                                                                  const int* __restrict__ csr_src,
                                                                  const float* __restrict__ W2,
                                                                  const float* __restrict__ b2,
                                                                  float* __restrict__ Out, int N) {
    __shared__ float w2sh[2048];        // W2 [32][64]
    __shared__ float aggsh[4][136];     // per-node, per-head stride 34
    int tid = threadIdx.x;
    {
        float4 v = ((const float4*)W2)[tid];
        *(float4*)&w2sh[tid * 4] = v;
        float4 v2 = ((const float4*)W2)[tid + 256];
        *(float4*)&w2sh[(tid + 256) * 4] = v2;
    }

    int lane = tid & 63;
    int nb = tid >> 6;
    int node = __builtin_amdgcn_readfirstlane(blockIdx.x * 4 + nb);
    bool active = node < N;
    int h = lane >> 4, f = lane & 15;
    if (active) {
        int start = __builtin_amdgcn_readfirstlane(row_off[node]);
        int end   = __builtin_amdgcn_readfirstlane(row_off[node + 1]);
        int deg = end - start;
        float adh = ad_[node * 4 + h];

        int clamp = (deg > 0) ? deg - 1 : 0;
        int vidx = csr_src[start + min(lane, clamp)];
        int m = min(deg, 64);

        float2 acc = make_float2(0.f, 0.f);
        float den = 0.f;
        int j = 0;
        for (; j + 4 <= m; j += 4) {
            int s0 = __builtin_amdgcn_readlane(vidx, j);
            int s1 = __builtin_amdgcn_readlane(vidx, j + 1);
            int s2 = __builtin_amdgcn_readlane(vidx, j + 2);
            int s3 = __builtin_amdgcn_readlane(vidx, j + 3);
            float a0 = as_[s0 * 4 + h], a1 = as_[s1 * 4 + h];
            float a2 = as_[s2 * 4 + h], a3 = as_[s3 * 4 + h];
            u32 u0 = O1[s0 * 16 + f];
            u32 u1 = O1[s1 * 16 + f];
            u32 u2 = O1[s2 * 16 + f];
            u32 u3 = O1[s3 * 16 + f];
            float e0 = lrelu_exp2(a0 + adh), e1 = lrelu_exp2(a1 + adh);
            float e2 = lrelu_exp2(a2 + adh), e3 = lrelu_exp2(a3 + adh);
            acc.x = fmaf(e0, bf_lo(u0), acc.x); acc.y = fmaf(e0, bf_hi(u0), acc.y); den += e0;
            acc.x = fmaf(e1, bf_lo(u1), acc.x); acc.y = fmaf(e1, bf_hi(u1), acc.y); den += e1;
            acc.x = fmaf(e2, bf_lo(u2), acc.x); acc.y = fmaf(e2, bf_hi(u2), acc.y); den += e2;
            acc.x = fmaf(e3, bf_lo(u3), acc.x); acc.y = fmaf(e3, bf_hi(u3), acc.y); den += e3;
        }
        for (; j < m; ++j) {
            int s = __builtin_amdgcn_readlane(vidx, j);
            float e = lrelu_exp2(as_[s * 4 + h] + adh);
            u32 u = O1[s * 16 + f];
            acc.x = fmaf(e, bf_lo(u), acc.x); acc.y = fmaf(e, bf_hi(u), acc.y); den += e;
        }
        for (int jj = start + 64; jj < end; ++jj) {
            int s = __builtin_amdgcn_readfirstlane(csr_src[jj]);
            float e = lrelu_exp2(as_[s * 4 + h] + adh);
            u32 u = O1[s * 16 + f];
            acc.x = fmaf(e, bf_lo(u), acc.x); acc.y = fmaf(e, bf_hi(u), acc.y); den += e;
        }
        float inv = 1.f / (den + EPS_GAT);
        aggsh[nb][h * 34 + f * 2]     = acc.x * inv;
        aggsh[nb][h * 34 + f * 2 + 1] = acc.y * inv;
    }
    __syncthreads();

    if (active) {
        int q = h, o = f;
        float s = 0.f;
#pragma unroll
        for (int k = 0; k < 32; ++k)
            s += aggsh[nb][q * 34 + k] * w2sh[k * 64 + q * 16 + o];
        s += __shfl_xor(s, 16);
        s += __shfl_xor(s, 32);
        if (lane < 16)
            Out[(size_t)node * 16 + o] = s * 0.25f + b2[o];
    }
}

// ---------------- launch ----------------

extern "C" void kernel_launch(void* const* d_in, const int* in_sizes, int n_in,
                              void* d_out, int out_size, void* d_ws, size_t ws_size,
                              hipStream_t stream) {
    const float* x      = (const float*)d_in[0];
    const int*   eidx   = (const int*)d_in[1];
    const float* W1     = (const float*)d_in[2];
    const float* a1_src = (const float*)d_in[3];
    const float* a1_dst = (const float*)d_in[4];
    const float* b1     = (const float*)d_in[5];
    const float* W2     = (const float*)d_in[6];
    const float* a2_src = (const float*)d_in[7];
    const float* a2_dst = (const float*)d_in[8];
    const float* b2     = (const float*)d_in[9];
    float* out = (float*)d_out;

    const int N = in_sizes[0] / 128;
    const int E = in_sizes[1] / 2;
    const int* src = eidx;
    const int* dst = eidx + E;

    char* base = (char*)d_ws;
    size_t off = 0;
    auto carve = [&](size_t bytes) -> char* {
        off = (off + 255) & ~(size_t)255;
        char* p = base + off;
        off += bytes;
        return p;
    };
    int* counts   = (int*)carve((size_t)N * 4);
    int* scanned  = (int*)carve((size_t)N * 4);
    int* bsums    = (int*)carve(1024 * 4);
    int* done     = (int*)carve(256);
    int* row_off  = (int*)carve((size_t)(N + 1) * 4);
    int* rank     = (int*)carve((size_t)E * 4);
    int* csr_src  = (int*)carve(((size_t)E + 64) * 4);
    u16* w1t_hi   = (u16*)carve(128 * 128 * 2);
    u16* w1t_lo   = (u16*)carve(128 * 128 * 2);
    u16* h1b      = (u16*)carve((size_t)N * 128 * 2);
    u32* out1b    = (u32*)carve((size_t)N * 16 * 4);
    float* as1  = (float*)carve((size_t)N * 4 * 4);
    float* ad1  = (float*)carve((size_t)N * 4 * 4);
    float* as2  = (float*)carve((size_t)N * 4 * 4);
    float* ad2  = (float*)carve((size_t)N * 4 * 4);
    float* w_as = (float*)carve(4 * 32 * 4);
    float* w_ad = (float*)carve(4 * 32 * 4);
    (void)ws_size; (void)n_in; (void)out_size;

    // 0) zero counts + done
    hipMemsetAsync(counts, 0, (size_t)N * 4, stream);
    hipMemsetAsync(done, 0, 4, stream);

    // 1) W1 split + W2 fold + degree histogram (one no-LDS kernel, full occupancy)
    prep_degree_kernel<<<65 + 2048, 256, 0, stream>>>(W1, w1t_hi, w1t_lo,
                                                      W2, a2_src, a2_dst, w_as, w_ad,
                                                      dst, E, counts, rank);

    // 2) GEMM1 + fused attn1
    gemm1_mfma_kernel<<<(N + 63) / 64, 256, 0, stream>>>(x, w1t_hi, w1t_lo, a1_src, a1_dst,
                                                         h1b, as1, ad1, N);

    // 3) scan (chunk scans + last-block partials scan)
    int nchunks = (N + 1023) / 1024;
    scan_kernel<<<nchunks, 1024, 0, stream>>>(counts, N, scanned, bsums, done, nchunks);

    // 4) fill CSR + finalize row_off
    {
        int total = (E > N + 1) ? E : (N + 1);
        fill_finalize_kernel<<<(total + 255) / 256, 256, 0, stream>>>(src, dst, E, N, counts,
                                                                      scanned, bsums, rank,
                                                                      row_off, csr_src);
    }

    // 5) layer-1 aggregate + fused attn2
    node_agg128_kernel<<<(N + 3) / 4, 256, 0, stream>>>((const u32*)h1b, as1, ad1,
                                                        row_off, csr_src, b1, w_as, w_ad,
                                                        out1b, as2, ad2, N);

    // 6) layer-2 aggregate + fused W2 epilogue
    node_agg32_fused_kernel<<<(N + 3) / 4, 256, 0, stream>>>(out1b, as2, ad2, row_off,
                                                             csr_src, W2, b2, out, N);
}

// Round 14
// 297.428 us; speedup vs baseline: 1.0726x; 1.0726x over previous
//
#include <hip/hip_runtime.h>
#include <math.h>

#define NEG_SLOPE 0.2f
#define EPS_GAT 1e-16f
#define LOG2E 1.4426950408889634f
typedef unsigned int u32;
typedef unsigned short u16;
typedef __attribute__((ext_vector_type(8))) short short8;   // 8 bf16 (4 VGPRs)
typedef __attribute__((ext_vector_type(4))) float f32x4;

// ---- bf16 helpers ----
__device__ inline u16 f2bf(float x) {
    union { float f; u32 u; } v; v.f = x;
    u32 r = v.u + 0x7FFFu + ((v.u >> 16) & 1u);   // RNE
    return (u16)(r >> 16);
}
__device__ inline float bf_lo(u32 u) {
    union { u32 i; float f; } v; v.i = u << 16; return v.f;
}
__device__ inline float bf_hi(u32 u) {
    union { u32 i; float f; } v; v.i = u & 0xFFFF0000u; return v.f;
}
__device__ inline float bf1(u16 s) {
    union { u32 i; float f; } v; v.i = ((u32)s) << 16; return v.f;
}
__device__ inline float fast_exp2(float x) {
#if __has_builtin(__builtin_amdgcn_exp2f)
    return __builtin_amdgcn_exp2f(x);
#else
    return exp2f(x);
#endif
}
// logits pre-scaled by LOG2E; lrelu commutes with positive scaling.
__device__ inline float lrelu_exp2(float t) {
    return fast_exp2(fmaxf(t, NEG_SLOPE * t));
}

// ---------------- CSR degree + (fused) weight prep ----------------
// blocks < degBlocks: degree+rank (one edge per thread). next 64: W1 hi/lo split. last: W2 fold.

__global__ void degree_prep_kernel(const int* __restrict__ dst, int E,
                                   int* __restrict__ counts, int* __restrict__ rank,
                                   const float* __restrict__ W1,
                                   u16* __restrict__ w1t_hi, u16* __restrict__ w1t_lo,
                                   const float* __restrict__ W2, const float* __restrict__ a2s,
                                   const float* __restrict__ a2d, float* __restrict__ w_as,
                                   float* __restrict__ w_ad, int degBlocks) {
    int b = blockIdx.x;
    if (b < degBlocks) {
        int e = b * 256 + threadIdx.x;
        if (e < E) rank[e] = atomicAdd(&counts[dst[e]], 1);
    } else if (b < degBlocks + 64) {
        int i = (b - degBlocks) * 256 + threadIdx.x;   // 16384
        int k = i >> 7, n = i & 127;
        float w = W1[i];
        u16 hi = f2bf(w);
        u16 lo = f2bf(w - bf1(hi));
        w1t_hi[n * 128 + k] = hi;
        w1t_lo[n * 128 + k] = lo;
    } else {
        int t = threadIdx.x;
        if (t < 128) {
            int h = t >> 5, k = t & 31;
            float s1 = 0.f, s2 = 0.f;
#pragma unroll
            for (int f = 0; f < 16; ++f) {
                float w = W2[k * 64 + h * 16 + f];
                s1 += w * a2s[h * 16 + f];
                s2 += w * a2d[h * 16 + f];
            }
            w_as[h * 32 + k] = s1;
            w_ad[h * 32 + k] = s2;
        }
    }
}

__global__ __launch_bounds__(1024) void scan_block_kernel(const int* __restrict__ counts, int N,
                                                          int* __restrict__ scanned, int* __restrict__ bsums) {
    __shared__ int tmp[1024];
    int i = blockIdx.x * 1024 + threadIdx.x;
    int v = (i < N) ? counts[i] : 0;
    tmp[threadIdx.x] = v;
    __syncthreads();
    for (int d = 1; d < 1024; d <<= 1) {
        int t = (threadIdx.x >= d) ? tmp[threadIdx.x - d] : 0;
        __syncthreads();
        tmp[threadIdx.x] += t;
        __syncthreads();
    }
    if (i < N) scanned[i] = tmp[threadIdx.x];
    if (threadIdx.x == 1023) bsums[blockIdx.x] = tmp[1023];
}

__global__ __launch_bounds__(256) void scan_partials_kernel(int* __restrict__ bsums, int nb) {
    __shared__ int tmp[256];
    int tid = threadIdx.x;
    int v = (tid < nb) ? bsums[tid] : 0;
    tmp[tid] = v;
    __syncthreads();
    for (int d = 1; d < 256; d <<= 1) {
        int t = (tid >= d) ? tmp[tid - d] : 0;
        __syncthreads();
        tmp[tid] += t;
        __syncthreads();
    }
    if (tid < nb) bsums[tid] = tmp[tid] - v;  // exclusive
}

__global__ void finalize_offsets_kernel(const int* __restrict__ scanned,
                                        const int* __restrict__ bsums_excl, int N,
                                        int* __restrict__ row_off) {
    int i = blockIdx.x * blockDim.x + threadIdx.x;
    if (i < N) {
        int incl = scanned[i] + bsums_excl[i >> 10];
        row_off[i + 1] = incl;
        if (i == 0) row_off[0] = 0;
    }
}

__global__ void fill_csr_kernel(const int* __restrict__ src, const int* __restrict__ dst, int E,
                                const int* __restrict__ row_off, const int* __restrict__ rank,
                                int* __restrict__ csr_src) {
    int e = blockIdx.x * blockDim.x + threadIdx.x;
    if (e < E) {
        int pos = row_off[dst[e]] + rank[e];
        csr_src[pos] = src[e];
    }
}

// ---------------- GEMM1 via MFMA + fused attn1 epilogue ----------------
// hi/lo split (3 MFMAs) = fp32-grade. After the K-loop, the h-tile is staged in
// LDS (aliasing the W-staging buffer — safe after the final barrier) and one
// thread per (row,head) computes the two 32-dots for as1/ad1 (pre-scaled LOG2E).

__global__ __launch_bounds__(256) void gemm1_mfma_kernel(const float* __restrict__ X,
                                                         const u16* __restrict__ w1t_hi,
                                                         const u16* __restrict__ w1t_lo,
                                                         const float* __restrict__ a_src,
                                                         const float* __restrict__ a_dst,
                                                         u16* __restrict__ Hb,
                                                         float* __restrict__ as_,
                                                         float* __restrict__ ad_, int N) {
    __shared__ u16 xsh_hi[64][40];
    __shared__ u16 xsh_lo[64][40];
    __shared__ u16 wbuf[10240];          // wsh_hi | wsh_lo; reused as h-tile after K-loop
    __shared__ float ash[128], adsh[128];
    u16* wsh_hi = wbuf;
    u16* wsh_lo = wbuf + 5120;
    int tid = threadIdx.x;
    int wave = tid >> 6, lane = tid & 63, quad = lane >> 4;
    int m0 = blockIdx.x * 64;

    if (tid < 128) { ash[tid] = a_src[tid]; adsh[tid] = a_dst[tid]; }

    f32x4 acc[4][2];
#pragma unroll
    for (int rt = 0; rt < 4; ++rt)
#pragma unroll
        for (int ct = 0; ct < 2; ++ct) acc[rt][ct] = (f32x4)(0.f);

    int xrow = tid >> 2, xkq = (tid & 3) * 8;

    for (int k0 = 0; k0 < 128; k0 += 32) {
        {
            int gr = m0 + xrow;
            float f[8];
            *(float4*)&f[0] = (gr < N) ? *(const float4*)(X + (size_t)gr * 128 + k0 + xkq)
                                       : make_float4(0.f, 0.f, 0.f, 0.f);
            *(float4*)&f[4] = (gr < N) ? *(const float4*)(X + (size_t)gr * 128 + k0 + xkq + 4)
                                       : make_float4(0.f, 0.f, 0.f, 0.f);
            u16 hi[8], lo[8];
#pragma unroll
            for (int i = 0; i < 8; ++i) {
                hi[i] = f2bf(f[i]);
                lo[i] = f2bf(f[i] - bf1(hi[i]));
            }
            *(uint4*)&xsh_hi[xrow][xkq] = *(uint4*)hi;
            *(uint4*)&xsh_lo[xrow][xkq] = *(uint4*)lo;
        }
        {
#pragma unroll
            for (int i = 0; i < 2; ++i) {
                int id = tid * 2 + i;
                int n = id >> 2, part = id & 3;
                *(uint4*)&wsh_hi[n * 40 + part * 8] =
                    ((const uint4*)(w1t_hi + n * 128 + k0))[part];
                *(uint4*)&wsh_lo[n * 40 + part * 8] =
                    ((const uint4*)(w1t_lo + n * 128 + k0))[part];
            }
        }
        __syncthreads();

        short8 bhi[2], blo[2];
#pragma unroll
        for (int ct = 0; ct < 2; ++ct) {
            int n = wave * 32 + ct * 16 + (lane & 15);
            bhi[ct] = *(const short8*)&wsh_hi[n * 40 + quad * 8];
            blo[ct] = *(const short8*)&wsh_lo[n * 40 + quad * 8];
        }
#pragma unroll
        for (int rt = 0; rt < 4; ++rt) {
            int m = rt * 16 + (lane & 15);
            short8 ahi = *(const short8*)&xsh_hi[m][quad * 8];
            short8 alo = *(const short8*)&xsh_lo[m][quad * 8];
#pragma unroll
            for (int ct = 0; ct < 2; ++ct) {
                acc[rt][ct] = __builtin_amdgcn_mfma_f32_16x16x32_bf16(ahi, bhi[ct], acc[rt][ct], 0, 0, 0);
                acc[rt][ct] = __builtin_amdgcn_mfma_f32_16x16x32_bf16(alo, bhi[ct], acc[rt][ct], 0, 0, 0);
                acc[rt][ct] = __builtin_amdgcn_mfma_f32_16x16x32_bf16(ahi, blo[ct], acc[rt][ct], 0, 0, 0);
            }
        }
        __syncthreads();
    }

    // h-tile -> global + LDS (stride 130 u16 per row; 16640 B <= 20480 B of wbuf)
    const int HS = 130;
#pragma unroll
    for (int rt = 0; rt < 4; ++rt)
#pragma unroll
        for (int ct = 0; ct < 2; ++ct) {
            int col = wave * 32 + ct * 16 + (lane & 15);
#pragma unroll
            for (int r = 0; r < 4; ++r) {
                int row = rt * 16 + quad * 4 + r;
                u16 hv = f2bf(acc[rt][ct][r]);
                int gr = m0 + row;
                if (gr < N) Hb[(size_t)gr * 128 + col] = hv;
                wbuf[row * HS + col] = hv;
            }
        }
    __syncthreads();

    // attn1: one thread per (row, head)
    {
        int row = tid >> 2, h = tid & 3;
        int gr = m0 + row;
        if (gr < N) {
            const u32* hr = (const u32*)&wbuf[row * HS + h * 32];   // 16 dwords
            float s1 = 0.f, s2 = 0.f;
#pragma unroll
            for (int q = 0; q < 16; ++q) {
                u32 u = hr[q];
                float flo = bf_lo(u), fhi = bf_hi(u);
                s1 += flo * ash[h * 32 + 2 * q] + fhi * ash[h * 32 + 2 * q + 1];
                s2 += flo * adsh[h * 32 + 2 * q] + fhi * adsh[h * 32 + 2 * q + 1];
            }
            as_[(size_t)gr * 4 + h] = s1 * LOG2E;
            ad_[(size_t)gr * 4 + h] = s2 * LOG2E;
        }
    }
}

// ---------------- layer-1 aggregate + fused attn2 epilogue ----------------

__global__ __launch_bounds__(256) void node_agg128_kernel(const u32* __restrict__ Hb,
                                                          const float* __restrict__ as_,
                                                          const float* __restrict__ ad_,
                                                          const int* __restrict__ row_off,
                                                          const int* __restrict__ csr_src,
                                                          const float* __restrict__ bias,
                                                          const float* __restrict__ w_as,
                                                          const float* __restrict__ w_ad,
                                                          u32* __restrict__ O1,
                                                          float* __restrict__ as2,
                                                          float* __restrict__ ad2, int N) {
    int lane = threadIdx.x & 63;
    int node = __builtin_amdgcn_readfirstlane(blockIdx.x * 4 + (threadIdx.x >> 6));
    if (node >= N) return;
    int start = __builtin_amdgcn_readfirstlane(row_off[node]);
    int end   = __builtin_amdgcn_readfirstlane(row_off[node + 1]);
    int deg = end - start;
    int h = lane >> 4;
    float adh = ad_[node * 4 + h];

    int clamp = (deg > 0) ? deg - 1 : 0;
    int vidx = csr_src[start + min(lane, clamp)];
    int m = min(deg, 64);

    float2 acc = make_float2(0.f, 0.f);
    float den = 0.f;
    int j = 0;
    for (; j + 4 <= m; j += 4) {
        int s0 = __builtin_amdgcn_readlane(vidx, j);
        int s1 = __builtin_amdgcn_readlane(vidx, j + 1);
        int s2 = __builtin_amdgcn_readlane(vidx, j + 2);
        int s3 = __builtin_amdgcn_readlane(vidx, j + 3);
        float a0 = as_[s0 * 4 + h], a1 = as_[s1 * 4 + h];
        float a2 = as_[s2 * 4 + h], a3 = as_[s3 * 4 + h];
        u32 u0 = Hb[s0 * 64 + lane];
        u32 u1 = Hb[s1 * 64 + lane];
        u32 u2 = Hb[s2 * 64 + lane];
        u32 u3 = Hb[s3 * 64 + lane];
        float e0 = lrelu_exp2(a0 + adh), e1 = lrelu_exp2(a1 + adh);
        float e2 = lrelu_exp2(a2 + adh), e3 = lrelu_exp2(a3 + adh);
        acc.x = fmaf(e0, bf_lo(u0), acc.x); acc.y = fmaf(e0, bf_hi(u0), acc.y); den += e0;
        acc.x = fmaf(e1, bf_lo(u1), acc.x); acc.y = fmaf(e1, bf_hi(u1), acc.y); den += e1;
        acc.x = fmaf(e2, bf_lo(u2), acc.x); acc.y = fmaf(e2, bf_hi(u2), acc.y); den += e2;
        acc.x = fmaf(e3, bf_lo(u3), acc.x); acc.y = fmaf(e3, bf_hi(u3), acc.y); den += e3;
    }
    for (; j < m; ++j) {
        int s = __builtin_amdgcn_readlane(vidx, j);
        float e = lrelu_exp2(as_[s * 4 + h] + adh);
        u32 u = Hb[s * 64 + lane];
        acc.x = fmaf(e, bf_lo(u), acc.x); acc.y = fmaf(e, bf_hi(u), acc.y); den += e;
    }
    for (int jj = start + 64; jj < end; ++jj) {   // deg>64 fallback
        int s = __builtin_amdgcn_readfirstlane(csr_src[jj]);
        float e = lrelu_exp2(as_[s * 4 + h] + adh);
        u32 u = Hb[s * 64 + lane];
        acc.x = fmaf(e, bf_lo(u), acc.x); acc.y = fmaf(e, bf_hi(u), acc.y); den += e;
    }
    float inv = 1.f / (den + EPS_GAT);
    float px = acc.x * inv, py = acc.y * inv;
    // butterfly head-sum: afterwards EVERY lane holds the 4-head sum for f=lane&15
    px += __shfl_xor(px, 16); py += __shfl_xor(py, 16);
    px += __shfl_xor(px, 32); py += __shfl_xor(py, 32);

    int f2 = (lane & 15) * 2;
    float2 bv = *(const float2*)&bias[f2];
    float ox = fmaxf(px * 0.25f + bv.x, 0.f);
    float oy = fmaxf(py * 0.25f + bv.y, 0.f);
    if (lane < 16)
        O1[node * 16 + lane] = (u32)f2bf(ox) | ((u32)f2bf(oy) << 16);

    // fused attn2 (16-lane xor reduction)
    int h2 = lane >> 4;
    float2 wa = *(const float2*)&w_as[h2 * 32 + f2];
    float2 wd = *(const float2*)&w_ad[h2 * 32 + f2];
    float ta = ox * wa.x + oy * wa.y;
    float td = ox * wd.x + oy * wd.y;
    ta += __shfl_xor(ta, 1); td += __shfl_xor(td, 1);
    ta += __shfl_xor(ta, 2); td += __shfl_xor(td, 2);
    ta += __shfl_xor(ta, 4); td += __shfl_xor(td, 4);
    ta += __shfl_xor(ta, 8); td += __shfl_xor(td, 8);
    if ((lane & 15) == 0) {
        as2[node * 4 + h2] = ta * LOG2E;
        ad2[node * 4 + h2] = td * LOG2E;
    }
}

// ---------------- layer-2 aggregate + fused W2 epilogue ----------------

__global__ __launch_bounds__(256) void node_agg32_fused_kernel(const u32* __restrict__ O1,
                                                               const float* __restrict__ as_,
                                                               const float* __restrict__ ad_,
                                                               const int* __restrict__ row_off,
                                                               const int* __restrict__ csr_src,
                                                               const float* __restrict__ W2,
                                                               const float* __restrict__ b2,
                                                               float* __restrict__ Out, int N) {
    __shared__ float w2sh[2048];        // W2 [32][64]
    __shared__ float aggsh[4][136];     // per-node, per-head stride 34
    int tid = threadIdx.x;
    {
        float4 v = ((const float4*)W2)[tid];
        *(float4*)&w2sh[tid * 4] = v;
        float4 v2 = ((const float4*)W2)[tid + 256];
        *(float4*)&w2sh[(tid + 256) * 4] = v2;
    }

    int lane = tid & 63;
    int nb = tid >> 6;
    int node = __builtin_amdgcn_readfirstlane(blockIdx.x * 4 + nb);
    bool active = node < N;
    int h = lane >> 4, f = lane & 15;
    if (active) {
        int start = __builtin_amdgcn_readfirstlane(row_off[node]);
        int end   = __builtin_amdgcn_readfirstlane(row_off[node + 1]);
        int deg = end - start;
        float adh = ad_[node * 4 + h];

        int clamp = (deg > 0) ? deg - 1 : 0;
        int vidx = csr_src[start + min(lane, clamp)];
        int m = min(deg, 64);

        float2 acc = make_float2(0.f, 0.f);
        float den = 0.f;
        int j = 0;
        for (; j + 4 <= m; j += 4) {
            int s0 = __builtin_amdgcn_readlane(vidx, j);
            int s1 = __builtin_amdgcn_readlane(vidx, j + 1);
            int s2 = __builtin_amdgcn_readlane(vidx, j + 2);
            int s3 = __builtin_amdgcn_readlane(vidx, j + 3);
            float a0 = as_[s0 * 4 + h], a1 = as_[s1 * 4 + h];
            float a2 = as_[s2 * 4 + h], a3 = as_[s3 * 4 + h];
            u32 u0 = O1[s0 * 16 + f];
            u32 u1 = O1[s1 * 16 + f];
            u32 u2 = O1[s2 * 16 + f];
            u32 u3 = O1[s3 * 16 + f];
            float e0 = lrelu_exp2(a0 + adh), e1 = lrelu_exp2(a1 + adh);
            float e2 = lrelu_exp2(a2 + adh), e3 = lrelu_exp2(a3 + adh);
            acc.x = fmaf(e0, bf_lo(u0), acc.x); acc.y = fmaf(e0, bf_hi(u0), acc.y); den += e0;
            acc.x = fmaf(e1, bf_lo(u1), acc.x); acc.y = fmaf(e1, bf_hi(u1), acc.y); den += e1;
            acc.x = fmaf(e2, bf_lo(u2), acc.x); acc.y = fmaf(e2, bf_hi(u2), acc.y); den += e2;
            acc.x = fmaf(e3, bf_lo(u3), acc.x); acc.y = fmaf(e3, bf_hi(u3), acc.y); den += e3;
        }
        for (; j < m; ++j) {
            int s = __builtin_amdgcn_readlane(vidx, j);
            float e = lrelu_exp2(as_[s * 4 + h] + adh);
            u32 u = O1[s * 16 + f];
            acc.x = fmaf(e, bf_lo(u), acc.x); acc.y = fmaf(e, bf_hi(u), acc.y); den += e;
        }
        for (int jj = start + 64; jj < end; ++jj) {
            int s = __builtin_amdgcn_readfirstlane(csr_src[jj]);
            float e = lrelu_exp2(as_[s * 4 + h] + adh);
            u32 u = O1[s * 16 + f];
            acc.x = fmaf(e, bf_lo(u), acc.x); acc.y = fmaf(e, bf_hi(u), acc.y); den += e;
        }
        float inv = 1.f / (den + EPS_GAT);
        aggsh[nb][h * 34 + f * 2]     = acc.x * inv;
        aggsh[nb][h * 34 + f * 2 + 1] = acc.y * inv;
    }
    __syncthreads();

    if (active) {
        int q = h, o = f;
        float s = 0.f;
#pragma unroll
        for (int k = 0; k < 32; ++k)
            s += aggsh[nb][q * 34 + k] * w2sh[k * 64 + q * 16 + o];
        s += __shfl_xor(s, 16);
        s += __shfl_xor(s, 32);
        if (lane < 16)
            Out[(size_t)node * 16 + o] = s * 0.25f + b2[o];
    }
}

// ---------------- launch ----------------

extern "C" void kernel_launch(void* const* d_in, const int* in_sizes, int n_in,
                              void* d_out, int out_size, void* d_ws, size_t ws_size,
                              hipStream_t stream) {
    const float* x      = (const float*)d_in[0];
    const int*   eidx   = (const int*)d_in[1];
    const float* W1     = (const float*)d_in[2];
    const float* a1_src = (const float*)d_in[3];
    const float* a1_dst = (const float*)d_in[4];
    const float* b1     = (const float*)d_in[5];
    const float* W2     = (const float*)d_in[6];
    const float* a2_src = (const float*)d_in[7];
    const float* a2_dst = (const float*)d_in[8];
    const float* b2     = (const float*)d_in[9];
    float* out = (float*)d_out;

    const int N = in_sizes[0] / 128;
    const int E = in_sizes[1] / 2;
    const int* src = eidx;
    const int* dst = eidx + E;

    char* base = (char*)d_ws;
    size_t off = 0;
    auto carve = [&](size_t bytes) -> char* {
        off = (off + 255) & ~(size_t)255;
        char* p = base + off;
        off += bytes;
        return p;
    };
    int* counts   = (int*)carve((size_t)N * 4);
    int* scanned  = (int*)carve((size_t)N * 4);
    int* bsums    = (int*)carve(256 * 4);
    int* row_off  = (int*)carve((size_t)(N + 1) * 4);
    int* rank     = (int*)carve((size_t)E * 4);
    int* csr_src  = (int*)carve((size_t)E * 4);
    u16* w1t_hi   = (u16*)carve(128 * 128 * 2);
    u16* w1t_lo   = (u16*)carve(128 * 128 * 2);
    u16* h1b      = (u16*)carve((size_t)N * 128 * 2);
    u32* out1b    = (u32*)carve((size_t)N * 16 * 4);
    float* as1  = (float*)carve((size_t)N * 4 * 4);
    float* ad1  = (float*)carve((size_t)N * 4 * 4);
    float* as2  = (float*)carve((size_t)N * 4 * 4);
    float* ad2  = (float*)carve((size_t)N * 4 * 4);
    float* w_as = (float*)carve(4 * 32 * 4);
    float* w_ad = (float*)carve(4 * 32 * 4);
    (void)ws_size; (void)n_in; (void)out_size;

    // --- CSR build + weight prep (fused grid) ---
    hipMemsetAsync(counts, 0, (size_t)N * 4, stream);
    int degBlocks = (E + 255) / 256;
    degree_prep_kernel<<<degBlocks + 65, 256, 0, stream>>>(dst, E, counts, rank,
                                                           W1, w1t_hi, w1t_lo,
                                                           W2, a2_src, a2_dst, w_as, w_ad,
                                                           degBlocks);
    int nb = (N + 1023) / 1024;
    scan_block_kernel<<<nb, 1024, 0, stream>>>(counts, N, scanned, bsums);
    scan_partials_kernel<<<1, 256, 0, stream>>>(bsums, nb);
    finalize_offsets_kernel<<<(N + 255) / 256, 256, 0, stream>>>(scanned, bsums, N, row_off);
    fill_csr_kernel<<<(E + 255) / 256, 256, 0, stream>>>(src, dst, E, row_off, rank, csr_src);

    // --- Layer 1 (GEMM + fused attn1) ---
    gemm1_mfma_kernel<<<(N + 63) / 64, 256, 0, stream>>>(x, w1t_hi, w1t_lo, a1_src, a1_dst,
                                                         h1b, as1, ad1, N);
    node_agg128_kernel<<<(N + 3) / 4, 256, 0, stream>>>((const u32*)h1b, as1, ad1,
                                                        row_off, csr_src, b1, w_as, w_ad,
                                                        out1b, as2, ad2, N);

    // --- Layer 2 (aggregate + fused W2 epilogue) ---
    node_agg32_fused_kernel<<<(N + 3) / 4, 256, 0, stream>>>(out1b, as2, ad2, row_off,
                                                             csr_src, W2, b2, out, N);
}